// Round 5
// baseline (87.893 us; speedup 1.0000x reference)
//
#include <hip/hip_runtime.h>

// crop_and_resize (RoIAlign-style bilinear), fp32, NHWC.
// feats: (8, 64, 64, 256) fp32 = 4 MiB/image; boxes: (4000,4); box_ind: (4000,)
// out:   (4000, 7, 7, 256) fp32
//
// R5: gather from a bf16 shadow of feats (built in d_ws) -> halves the
// dominant L2->CU gather traffic (4 KiB -> 2 KiB per cell). Lerp in fp32.
// XCD-locality kept: image i pinned to blocks with blockIdx.x % 8 == i.
// Falls back to fp32 gather if ws_size is too small for the shadow copy.

#define H 64
#define W 64
#define C 256
#define CROP_HW 49  // 7*7
#define NIMG 8

typedef float          f32x4 __attribute__((ext_vector_type(4)));
typedef unsigned short u16x4 __attribute__((ext_vector_type(4)));

// ---- kernel 0: fp32 -> bf16 (RNE) shadow copy of feats --------------------
__device__ __forceinline__ unsigned short f2bf(float f) {
    unsigned u = __float_as_uint(f);
    unsigned r = (u + 0x7fffu + ((u >> 16) & 1u)) >> 16;  // round-nearest-even
    return (unsigned short)r;
}

__global__ __launch_bounds__(256) void convert_bf16_kernel(
    const float* __restrict__ in, unsigned short* __restrict__ outb, int n4)
{
    const f32x4* __restrict__ in4 = reinterpret_cast<const f32x4*>(in);
    u16x4* __restrict__ ob = reinterpret_cast<u16x4*>(outb);
    int i = blockIdx.x * blockDim.x + threadIdx.x;
    const int stride = gridDim.x * blockDim.x;
    for (; i < n4; i += stride) {
        const f32x4 v = in4[i];
        u16x4 r;
        r.x = f2bf(v.x); r.y = f2bf(v.y); r.z = f2bf(v.z); r.w = f2bf(v.w);
        ob[i] = r;
    }
}

// ---- kernel 1: stable bucket of box indices by image ----------------------
__global__ __launch_bounds__(512) void bucket_kernel(
    const int* __restrict__ box_ind,
    int* __restrict__ order,     // [n] box ids grouped by image (stable)
    int* __restrict__ offsets,   // [9] bucket offsets
    int n)
{
    const int wave = threadIdx.x >> 6;   // 0..7 == image id
    const int lane = threadIdx.x & 63;
    __shared__ int counts[NIMG];

    int cnt = 0;
    for (int i = lane; i < n; i += 64)
        cnt += (box_ind[i] == wave);
    for (int off = 32; off; off >>= 1)
        cnt += __shfl_down(cnt, off);
    if (lane == 0) counts[wave] = cnt;
    __syncthreads();

    int start = 0;
    for (int i = 0; i < wave; ++i) start += counts[i];
    if (threadIdx.x == 0) {
        int acc = 0;
        for (int i = 0; i < NIMG; ++i) { offsets[i] = acc; acc += counts[i]; }
        offsets[NIMG] = acc;
    }

    int pos = start;
    for (int base = 0; base < n; base += 64) {
        const int i = base + lane;
        const bool m = (i < n) && (box_ind[i] == wave);
        const unsigned long long mask = __ballot(m);
        const int below = __popcll(mask & ((1ULL << lane) - 1ULL));
        if (m) order[pos + below] = i;
        pos += __popcll(mask);
    }
}

// ---- per-cell geometry -----------------------------------------------------
struct Cell {
    int p00, p01, p10, p11;   // pixel indices (y*W+x) within image
    float wx, wy;
    bool valid;
    size_t oidx;              // float4-granular output index (without lane)
};

__device__ __forceinline__ Cell cell_info(
    int c, const int* __restrict__ order, const float* __restrict__ boxes,
    int start)
{
    Cell k;
    const int bi = c / CROP_HW;
    const int r  = c - bi * CROP_HW;
    const int iy = r / 7;
    const int ix = r - iy * 7;
    const int b  = order[start + bi];

    const float by1 = boxes[b * 4 + 0];
    const float bx1 = boxes[b * 4 + 1];
    const float by2 = boxes[b * 4 + 2];
    const float bx2 = boxes[b * 4 + 3];

    // reference order: step = (hi-lo)*(extent-1)/(n-1); s = lo*(extent-1)+i*step
    const float stepy = (by2 - by1) * 63.0f / 6.0f;
    const float stepx = (bx2 - bx1) * 63.0f / 6.0f;
    const float ys = by1 * 63.0f + (float)iy * stepy;
    const float xs = bx1 * 63.0f + (float)ix * stepx;

    const float y0f = floorf(ys);
    const float x0f = floorf(xs);
    k.wy = ys - y0f;
    k.wx = xs - x0f;

    const int y0 = min(max((int)y0f, 0), H - 1);
    const int y1 = min(y0 + 1, H - 1);
    const int x0 = min(max((int)x0f, 0), W - 1);
    const int x1 = min(x0 + 1, W - 1);

    k.valid = (ys >= 0.0f) && (ys <= (float)(H - 1)) &&
              (xs >= 0.0f) && (xs <= (float)(W - 1));

    k.p00 = y0 * W + x0;
    k.p01 = y0 * W + x1;
    k.p10 = y1 * W + x0;
    k.p11 = y1 * W + x1;

    k.oidx = (size_t)b * CROP_HW * (C / 4) + (size_t)r * (C / 4);
    return k;
}

__device__ __forceinline__ f32x4 bf4_to_f32(u16x4 h) {
    f32x4 r;
    r.x = __uint_as_float((unsigned)h.x << 16);
    r.y = __uint_as_float((unsigned)h.y << 16);
    r.z = __uint_as_float((unsigned)h.z << 16);
    r.w = __uint_as_float((unsigned)h.w << 16);
    return r;
}

__device__ __forceinline__ f32x4 lerp2(const f32x4& v00, const f32x4& v01,
                                       const f32x4& v10, const f32x4& v11,
                                       float wx, float wy, bool valid)
{
    const f32x4 top = v00 + (v01 - v00) * wx;
    const f32x4 bot = v10 + (v11 - v10) * wx;
    f32x4 res = top + (bot - top) * wy;
    if (!valid) res = (f32x4)0.0f;
    return res;
}

// ---- kernel 2a: bilinear crop from bf16 shadow, XCD-partitioned -----------
__global__ __launch_bounds__(256) void crop_resize_bf16(
    const unsigned short* __restrict__ featsb,
    const float* __restrict__ boxes,
    const int*   __restrict__ order,
    const int*   __restrict__ offsets,
    float*       __restrict__ out)
{
    const int img  = blockIdx.x & 7;     // block->XCD round-robin heuristic
    const int slot = blockIdx.x >> 3;
    const int lane = threadIdx.x & 63;
    const int wv   = threadIdx.x >> 6;   // 0..3

    const int start  = offsets[img];
    const int nb     = offsets[img + 1] - start;
    const int ncells = nb * CROP_HW;
    const int npairs = (ncells + 1) >> 1;
    const int wave_local = slot * 4 + wv;
    const int stride     = (gridDim.x >> 3) * 4;

    // u16x4-granular: pixel p's lane-chunk = p*(C/4) + lane
    const u16x4* __restrict__ f4 = reinterpret_cast<const u16x4*>(featsb)
                                   + (size_t)img * (H * W * (C / 4));
    f32x4* __restrict__ o4 = reinterpret_cast<f32x4*>(out);

    for (int p = wave_local; p < npairs; p += stride) {
        const int  c0    = p * 2;
        const bool haveB = (c0 + 1 < ncells);          // wave-uniform
        const int  c1    = haveB ? c0 + 1 : c0;

        const Cell a  = cell_info(c0, order, boxes, start);
        const Cell bb = cell_info(c1, order, boxes, start);

        // issue all 8 gathers (dwordx2 each) before any lerp
        const u16x4 a00 = f4[a.p00  * (C / 4) + lane];
        const u16x4 a01 = f4[a.p01  * (C / 4) + lane];
        const u16x4 a10 = f4[a.p10  * (C / 4) + lane];
        const u16x4 a11 = f4[a.p11  * (C / 4) + lane];
        const u16x4 b00 = f4[bb.p00 * (C / 4) + lane];
        const u16x4 b01 = f4[bb.p01 * (C / 4) + lane];
        const u16x4 b10 = f4[bb.p10 * (C / 4) + lane];
        const u16x4 b11 = f4[bb.p11 * (C / 4) + lane];

        const f32x4 resA = lerp2(bf4_to_f32(a00), bf4_to_f32(a01),
                                 bf4_to_f32(a10), bf4_to_f32(a11),
                                 a.wx, a.wy, a.valid);
        __builtin_nontemporal_store(resA, &o4[a.oidx + lane]);

        if (haveB) {
            const f32x4 resB = lerp2(bf4_to_f32(b00), bf4_to_f32(b01),
                                     bf4_to_f32(b10), bf4_to_f32(b11),
                                     bb.wx, bb.wy, bb.valid);
            __builtin_nontemporal_store(resB, &o4[bb.oidx + lane]);
        }
    }
}

// ---- kernel 2b: fp32 fallback (identical structure, gathers fp32) ---------
__global__ __launch_bounds__(256) void crop_resize_f32(
    const float* __restrict__ feats,
    const float* __restrict__ boxes,
    const int*   __restrict__ order,
    const int*   __restrict__ offsets,
    float*       __restrict__ out)
{
    const int img  = blockIdx.x & 7;
    const int slot = blockIdx.x >> 3;
    const int lane = threadIdx.x & 63;
    const int wv   = threadIdx.x >> 6;

    const int start  = offsets[img];
    const int nb     = offsets[img + 1] - start;
    const int ncells = nb * CROP_HW;
    const int npairs = (ncells + 1) >> 1;
    const int wave_local = slot * 4 + wv;
    const int stride     = (gridDim.x >> 3) * 4;

    const f32x4* __restrict__ f4 = reinterpret_cast<const f32x4*>(feats)
                                   + (size_t)img * (H * W * (C / 4));
    f32x4* __restrict__ o4 = reinterpret_cast<f32x4*>(out);

    for (int p = wave_local; p < npairs; p += stride) {
        const int  c0    = p * 2;
        const bool haveB = (c0 + 1 < ncells);
        const int  c1    = haveB ? c0 + 1 : c0;

        const Cell a  = cell_info(c0, order, boxes, start);
        const Cell bb = cell_info(c1, order, boxes, start);

        const f32x4 a00 = f4[a.p00  * (C / 4) + lane];
        const f32x4 a01 = f4[a.p01  * (C / 4) + lane];
        const f32x4 a10 = f4[a.p10  * (C / 4) + lane];
        const f32x4 a11 = f4[a.p11  * (C / 4) + lane];
        const f32x4 b00 = f4[bb.p00 * (C / 4) + lane];
        const f32x4 b01 = f4[bb.p01 * (C / 4) + lane];
        const f32x4 b10 = f4[bb.p10 * (C / 4) + lane];
        const f32x4 b11 = f4[bb.p11 * (C / 4) + lane];

        const f32x4 resA = lerp2(a00, a01, a10, a11, a.wx, a.wy, a.valid);
        __builtin_nontemporal_store(resA, &o4[a.oidx + lane]);

        if (haveB) {
            const f32x4 resB = lerp2(b00, b01, b10, b11, bb.wx, bb.wy, bb.valid);
            __builtin_nontemporal_store(resB, &o4[bb.oidx + lane]);
        }
    }
}

extern "C" void kernel_launch(void* const* d_in, const int* in_sizes, int n_in,
                              void* d_out, int out_size, void* d_ws, size_t ws_size,
                              hipStream_t stream) {
    const float* feats   = (const float*)d_in[0];
    const float* boxes   = (const float*)d_in[1];
    const int*   box_ind = (const int*)d_in[2];
    float*       out     = (float*)d_out;

    const int n_boxes = in_sizes[1] / 4;
    const int n_feats = in_sizes[0];               // 8*64*64*256

    int* order   = (int*)d_ws;                     // n_boxes ints
    int* offsets = order + n_boxes;                // 9 ints
    const size_t bf_off   = 64 * 1024;             // aligned shadow offset
    const size_t bf_bytes = (size_t)n_feats * 2;
    unsigned short* featsb = (unsigned short*)((char*)d_ws + bf_off);

    bucket_kernel<<<1, 512, 0, stream>>>(box_ind, order, offsets, n_boxes);

    if (ws_size >= bf_off + bf_bytes) {
        convert_bf16_kernel<<<512, 256, 0, stream>>>(feats, featsb, n_feats / 4);
        crop_resize_bf16<<<2048, 256, 0, stream>>>(featsb, boxes, order, offsets, out);
    } else {
        crop_resize_f32<<<2048, 256, 0, stream>>>(feats, boxes, order, offsets, out);
    }
}

// Round 6
// 85.602 us; speedup vs baseline: 1.0268x; 1.0268x over previous
//
#include <hip/hip_runtime.h>

// crop_and_resize (RoIAlign-style bilinear), fp32, NHWC.
// feats: (8, 64, 64, 256) fp32 = 4 MiB/image; boxes: (4000,4); box_ind: (4000,)
// out:   (4000, 7, 7, 256) fp32
//
// R6: A/B on the store path. R3-R5 showed the crop kernel is flat (~69us)
// under gather-side changes (MLP x2, bytes /2) => theory: bound by the
// nontemporal-store path at ~2.8 TB/s. This round: PLAIN stores (L2
// write-back), everything else = R4 structure (fp32 gathers, XCD partition,
// 2 cells/iter). Box metadata loads merged into one float4 load.

#define H 64
#define W 64
#define C 256
#define CROP_HW 49  // 7*7
#define NIMG 8

typedef float f32x4 __attribute__((ext_vector_type(4)));

// ---- kernel 1: stable bucket of box indices by image ----------------------
__global__ __launch_bounds__(512) void bucket_kernel(
    const int* __restrict__ box_ind,
    int* __restrict__ order,     // [n] box ids grouped by image (stable)
    int* __restrict__ offsets,   // [9] bucket offsets
    int n)
{
    const int wave = threadIdx.x >> 6;   // 0..7 == image id
    const int lane = threadIdx.x & 63;
    __shared__ int counts[NIMG];

    int cnt = 0;
    for (int i = lane; i < n; i += 64)
        cnt += (box_ind[i] == wave);
    for (int off = 32; off; off >>= 1)
        cnt += __shfl_down(cnt, off);
    if (lane == 0) counts[wave] = cnt;
    __syncthreads();

    int start = 0;
    for (int i = 0; i < wave; ++i) start += counts[i];
    if (threadIdx.x == 0) {
        int acc = 0;
        for (int i = 0; i < NIMG; ++i) { offsets[i] = acc; acc += counts[i]; }
        offsets[NIMG] = acc;
    }

    int pos = start;
    for (int base = 0; base < n; base += 64) {
        const int i = base + lane;
        const bool m = (i < n) && (box_ind[i] == wave);
        const unsigned long long mask = __ballot(m);
        const int below = __popcll(mask & ((1ULL << lane) - 1ULL));
        if (m) order[pos + below] = i;
        pos += __popcll(mask);
    }
}

// ---- per-cell geometry ------------------------------------------------------
struct Cell {
    int i00, i01, i10, i11;   // float4-granular feats indices (within image)
    float wx, wy;
    bool valid;
    size_t oidx;              // float4-granular output index (without lane)
};

__device__ __forceinline__ Cell cell_info(
    int c, const int* __restrict__ order, const f32x4* __restrict__ boxes4,
    int start, int lane)
{
    Cell k;
    const int bi = c / CROP_HW;
    const int r  = c - bi * CROP_HW;
    const int iy = r / 7;
    const int ix = r - iy * 7;
    const int b  = order[start + bi];

    const f32x4 bx = boxes4[b];   // {y1, x1, y2, x2} in one dwordx4

    // reference order: step = (hi-lo)*(extent-1)/(n-1); s = lo*(extent-1)+i*step
    const float stepy = (bx.z - bx.x) * 63.0f / 6.0f;
    const float stepx = (bx.w - bx.y) * 63.0f / 6.0f;
    const float ys = bx.x * 63.0f + (float)iy * stepy;
    const float xs = bx.y * 63.0f + (float)ix * stepx;

    const float y0f = floorf(ys);
    const float x0f = floorf(xs);
    k.wy = ys - y0f;
    k.wx = xs - x0f;

    const int y0 = min(max((int)y0f, 0), H - 1);
    const int y1 = min(y0 + 1, H - 1);
    const int x0 = min(max((int)x0f, 0), W - 1);
    const int x1 = min(x0 + 1, W - 1);

    k.valid = (ys >= 0.0f) && (ys <= (float)(H - 1)) &&
              (xs >= 0.0f) && (xs <= (float)(W - 1));

    k.i00 = (y0 * W + x0) * (C / 4) + lane;
    k.i01 = (y0 * W + x1) * (C / 4) + lane;
    k.i10 = (y1 * W + x0) * (C / 4) + lane;
    k.i11 = (y1 * W + x1) * (C / 4) + lane;

    k.oidx = (size_t)b * CROP_HW * (C / 4) + (size_t)r * (C / 4);
    return k;
}

__device__ __forceinline__ f32x4 lerp2(const f32x4& v00, const f32x4& v01,
                                       const f32x4& v10, const f32x4& v11,
                                       float wx, float wy, bool valid)
{
    const f32x4 top = v00 + (v01 - v00) * wx;
    const f32x4 bot = v10 + (v11 - v10) * wx;
    f32x4 res = top + (bot - top) * wy;
    if (!valid) res = (f32x4)0.0f;
    return res;
}

// ---- kernel 2: bilinear crop, XCD-partitioned, 2 cells/iter, PLAIN stores --
__global__ __launch_bounds__(256) void crop_resize_xcd(
    const float* __restrict__ feats,
    const float* __restrict__ boxes,
    const int*   __restrict__ order,
    const int*   __restrict__ offsets,
    float*       __restrict__ out)
{
    const int img  = blockIdx.x & 7;     // block->XCD round-robin heuristic
    const int slot = blockIdx.x >> 3;
    const int lane = threadIdx.x & 63;
    const int wv   = threadIdx.x >> 6;   // 0..3

    const int start  = offsets[img];
    const int nb     = offsets[img + 1] - start;
    const int ncells = nb * CROP_HW;
    const int npairs = (ncells + 1) >> 1;
    const int wave_local = slot * 4 + wv;
    const int stride     = (gridDim.x >> 3) * 4;

    const f32x4* __restrict__ f4 = reinterpret_cast<const f32x4*>(feats)
                                   + (size_t)img * (H * W * (C / 4));
    const f32x4* __restrict__ boxes4 = reinterpret_cast<const f32x4*>(boxes);
    f32x4* __restrict__ o4 = reinterpret_cast<f32x4*>(out);

    for (int p = wave_local; p < npairs; p += stride) {
        const int  c0    = p * 2;
        const bool haveB = (c0 + 1 < ncells);          // wave-uniform
        const int  c1    = haveB ? c0 + 1 : c0;        // duplicate loads if tail

        const Cell a  = cell_info(c0, order, boxes4, start, lane);
        const Cell bb = cell_info(c1, order, boxes4, start, lane);

        // issue all 8 gathers before any lerp
        const f32x4 a00 = f4[a.i00];
        const f32x4 a01 = f4[a.i01];
        const f32x4 a10 = f4[a.i10];
        const f32x4 a11 = f4[a.i11];
        const f32x4 b00 = f4[bb.i00];
        const f32x4 b01 = f4[bb.i01];
        const f32x4 b10 = f4[bb.i10];
        const f32x4 b11 = f4[bb.i11];

        const f32x4 resA = lerp2(a00, a01, a10, a11, a.wx, a.wy, a.valid);
        o4[a.oidx + lane] = resA;                      // plain store (L2 WB)

        if (haveB) {
            const f32x4 resB = lerp2(b00, b01, b10, b11, bb.wx, bb.wy, bb.valid);
            o4[bb.oidx + lane] = resB;                 // plain store (L2 WB)
        }
    }
}

extern "C" void kernel_launch(void* const* d_in, const int* in_sizes, int n_in,
                              void* d_out, int out_size, void* d_ws, size_t ws_size,
                              hipStream_t stream) {
    const float* feats   = (const float*)d_in[0];
    const float* boxes   = (const float*)d_in[1];
    const int*   box_ind = (const int*)d_in[2];
    float*       out     = (float*)d_out;

    const int n_boxes = in_sizes[1] / 4;

    int* order   = (int*)d_ws;            // n_boxes ints
    int* offsets = order + n_boxes;       // 9 ints

    bucket_kernel<<<1, 512, 0, stream>>>(box_ind, order, offsets, n_boxes);

    // 2048 blocks x 256 threads; 256 blocks (1024 waves) per image.
    crop_resize_xcd<<<2048, 256, 0, stream>>>(feats, boxes, order, offsets, out);
}